// Round 1
// baseline (62.450 us; speedup 1.0000x reference)
//
#include <hip/hip_runtime.h>
#include <math.h>

#define NL 16

typedef float v2f __attribute__((ext_vector_type(2)));

// R(gm2,a)/R(gm5,a)/R(gm7,a) are real SO(3) plane rotations; the composed
// per-angle-triple matrix M = R7(a2) @ R5(a1) @ R2(a0) is:
//  row0 = [ c1*c0,              c1*s0,              s1    ]
//  row1 = [-c2*s0 - s2*s1*c0,   c2*c0 - s2*s1*s0,   s2*c1 ]
//  row2 = [ s2*s0 - c2*s1*c0,  -s2*c0 - c2*s1*s0,   c2*c1 ]
// Initial state e0 is real -> whole circuit is real 3-vector math.
// Chain cost is the algebraic floor: 18 FMA/sample/layer (matvec), packed
// 2 samples/lane -> 36 v_pk_fma_f32 per layer per thread (4 samples).

__global__ __launch_bounds__(256) void qnn_kernel(
    const float* __restrict__ batch,
    const float* __restrict__ weights,
    float* __restrict__ out,
    int nquads)
{
    __shared__ float4 Vs[NL][3];   // row r of V_l in .x/.y/.z

    const int t  = blockIdx.x * blockDim.x + threadIdx.x;   // quad index (4 samples)
    const int tc = t < nquads ? t : nquads - 1;             // clamp: no divergent return pre-barrier

    // Issue global loads first: HBM latency overlaps the V-build sincos
    // chain and the barrier wait instead of serializing after it.
    const float4* __restrict__ b4 = (const float4*)batch;
    const float4 q0 = b4[3 * tc + 0];
    const float4 q1 = b4[3 * tc + 1];
    const float4 q2 = b4[3 * tc + 2];

    if (threadIdx.x < NL) {
        const int l = threadIdx.x;
        const float a0 = weights[l * 6 + 0];
        const float a1 = weights[l * 6 + 1];
        const float a2 = weights[l * 6 + 2];
        float s0, c0, s1, c1, s2, c2;
        __sincosf(a0, &s0, &c0);
        __sincosf(a1, &s1, &c1);
        __sincosf(a2, &s2, &c2);
        Vs[l][0] = make_float4(c1 * c0, c1 * s0, s1, 0.f);
        Vs[l][1] = make_float4(-c2 * s0 - s2 * s1 * c0, c2 * c0 - s2 * s1 * s0, s2 * c1, 0.f);
        Vs[l][2] = make_float4(s2 * s0 - c2 * s1 * c0, -s2 * c0 - c2 * s1 * s0, c2 * c1, 0.f);
    }
    __syncthreads();

    const float xs[4][3] = {
        {q0.x, q0.y, q0.z},
        {q0.w, q1.x, q1.y},
        {q1.z, q1.w, q2.x},
        {q2.y, q2.z, q2.w},
    };

    // Build per-sample-pair encoding matrices directly in packed (v2f)
    // arithmetic: 2 pk_mul + 12 pk ops per pack vs 4x scalar builds + movs.
    v2f U[2][9];
    v2f S0[2], S1[2], S2[2];
    #pragma unroll
    for (int p = 0; p < 2; p++) {
        float sA0, cA0, sA1, cA1, sA2, cA2;
        float sB0, cB0, sB1, cB1, sB2, cB2;
        __sincosf(xs[2 * p][0],     &sA0, &cA0);
        __sincosf(xs[2 * p][1],     &sA1, &cA1);
        __sincosf(xs[2 * p][2],     &sA2, &cA2);
        __sincosf(xs[2 * p + 1][0], &sB0, &cB0);
        __sincosf(xs[2 * p + 1][1], &sB1, &cB1);
        __sincosf(xs[2 * p + 1][2], &sB2, &cB2);
        v2f s0 = {sA0, sB0}, c0 = {cA0, cB0};
        v2f s1 = {sA1, sB1}, c1 = {cA1, cB1};
        v2f s2 = {sA2, sB2}, c2 = {cA2, cB2};
        v2f a = s2 * s1;            // sin2*sin1
        v2f b = c2 * s1;            // cos2*sin1
        U[p][0] = c1 * c0;
        U[p][1] = c1 * s0;
        U[p][2] = s1;
        U[p][3] = -c2 * s0 - a * c0;
        U[p][4] = c2 * c0 - a * s0;
        U[p][5] = s2 * c1;
        U[p][6] = s2 * s0 - b * c0;
        U[p][7] = -s2 * c0 - b * s0;
        U[p][8] = c2 * c1;
        S0[p] = (v2f){1.f, 1.f};
        S1[p] = (v2f){0.f, 0.f};
        S2[p] = (v2f){0.f, 0.f};
    }

    // 16-layer chain on v_pk_fma_f32 (dual fp32 FMA), V rows broadcast
    // from LDS (same address across all lanes -> conflict-free broadcast).
    #pragma unroll
    for (int l = 0; l < NL; l++) {
        const float4 r0 = Vs[l][0];
        const float4 r1 = Vs[l][1];
        const float4 r2 = Vs[l][2];
        #pragma unroll
        for (int p = 0; p < 2; p++) {
            v2f t0 = U[p][0] * S0[p] + U[p][1] * S1[p] + U[p][2] * S2[p];
            v2f t1 = U[p][3] * S0[p] + U[p][4] * S1[p] + U[p][5] * S2[p];
            v2f t2 = U[p][6] * S0[p] + U[p][7] * S1[p] + U[p][8] * S2[p];
            S0[p] = r0.x * t0 + r0.y * t1 + r0.z * t2;
            S1[p] = r1.x * t0 + r1.y * t1 + r1.z * t2;
            S2[p] = r2.x * t0 + r2.y * t1 + r2.z * t2;
        }
    }

    // fid_k = (max(|s_k|, 1e-5) + 2e-5)^2 ; out = fid / sum(fid)
    // Packed epilogue: abs/max/add/square/scale as v_pk_* ops.
    float ov[12];
    #pragma unroll
    for (int p = 0; p < 2; p++) {
        const v2f eps  = {1e-5f, 1e-5f};
        const v2f eps2 = {2e-5f, 2e-5f};
        v2f a0 = __builtin_elementwise_max(__builtin_elementwise_abs(S0[p]), eps) + eps2;
        v2f a1 = __builtin_elementwise_max(__builtin_elementwise_abs(S1[p]), eps) + eps2;
        v2f a2 = __builtin_elementwise_max(__builtin_elementwise_abs(S2[p]), eps) + eps2;
        v2f f0 = a0 * a0;
        v2f f1 = a1 * a1;
        v2f f2 = a2 * a2;
        v2f s  = f0 + f1 + f2;
        v2f inv = {__builtin_amdgcn_rcpf(s.x), __builtin_amdgcn_rcpf(s.y)};
        v2f o0 = f0 * inv, o1 = f1 * inv, o2 = f2 * inv;
        ov[6 * p + 0] = o0.x; ov[6 * p + 1] = o1.x; ov[6 * p + 2] = o2.x;
        ov[6 * p + 3] = o0.y; ov[6 * p + 4] = o1.y; ov[6 * p + 5] = o2.y;
    }

    if (t < nquads) {
        float4* __restrict__ o4 = (float4*)out;
        o4[3 * t + 0] = make_float4(ov[0], ov[1], ov[2],  ov[3]);
        o4[3 * t + 1] = make_float4(ov[4], ov[5], ov[6],  ov[7]);
        o4[3 * t + 2] = make_float4(ov[8], ov[9], ov[10], ov[11]);
    }
}

extern "C" void kernel_launch(void* const* d_in, const int* in_sizes, int n_in,
                              void* d_out, int out_size, void* d_ws, size_t ws_size,
                              hipStream_t stream) {
    const float* batch   = (const float*)d_in[0];   // [B,3] fp32
    const float* weights = (const float*)d_in[1];   // [16,6] fp32
    float* out = (float*)d_out;                     // [B,3] fp32

    const int B = in_sizes[0] / 3;                  // 524288
    const int nquads = B / 4;
    const int block = 256;
    const int grid = (nquads + block - 1) / block;  // 512 blocks

    qnn_kernel<<<grid, block, 0, stream>>>(batch, weights, out, nquads);
}